// Round 15
// baseline (121.629 us; speedup 1.0000x reference)
//
#include <hip/hip_runtime.h>

#define VOCAB 10000
#define EMB   16
#define HID   32
#define BATCH 4096
#define TLEN  512

typedef _Float16 f16x4 __attribute__((ext_vector_type(4)));
typedef _Float16 f16x2 __attribute__((ext_vector_type(2)));
typedef float    f32x4 __attribute__((ext_vector_type(4)));

// ---------------------------------------------------------------------------
// Kernel 1: P[v][j] = b[j] + sum_e emb[v][e] * Wx[e][j]   (fp32 table in ws)
// ---------------------------------------------------------------------------
__global__ __launch_bounds__(256) void rnn_proj(
    const float* __restrict__ emb, const float* __restrict__ Wx,
    const float* __restrict__ bias, float* __restrict__ P)
{
    int tid = blockIdx.x * 256 + threadIdx.x;
    if (tid >= VOCAB * HID) return;
    int v = tid >> 5;
    int j = tid & 31;
    float acc = bias[j];
    const float* ev = emb + v * EMB;
#pragma unroll
    for (int e = 0; e < EMB; ++e) {
        acc = fmaf(ev[e], Wx[e * HID + j], acc);
    }
    P[tid] = acc;
}

// ---------------------------------------------------------------------------
// Kernel 2: self-feeding MFMA scan, chain-shortened.
// One wave = 16 batches (4096/16 = 256 waves; occupancy is structurally
// capped — the play is minimizing the per-step dependency chain).
//   z^T[j][b] = P^T[j][b] + sum_i Wh^T[j][i] * h^T[i][b]
// Layout identity (verified r13, absmax 3.9e-3): D frag == B frag, so
// D -> tanh -> cvt_pkrtz -> next B is lane-local. No LDS, no shuffles.
//
// r13 -> r15 chain surgery: the two k-half MFMAs per output-half were
// CHAINED through C (2x mfma dep-latency); now they are independent
// (C=P / C=0) + one f32x4 add. All 4 MFMAs per step issue back-to-back,
// and tanh(z0) overlaps z1's completion. Chain ~= 1 mfma-lat + tanh + pack.
// ---------------------------------------------------------------------------
__global__ __launch_bounds__(64)
void rnn_scan(
    const int*   __restrict__ x,   const float* __restrict__ P,
    const float* __restrict__ Wh,  const float* __restrict__ Wd,
    const float* __restrict__ bd,  float* __restrict__ out)
{
    const int l  = threadIdx.x & 63;
    const int bq = l & 15;                      // batch within tile / A-row j
    const int kg = l >> 4;                      // k-group: k/j-quad = 4*kg..+3
    const int bt = blockIdx.x * 16;             // batch tile base

    // A = Wh^T fragments: lane holds A[row][k] = Wh[k][row], k = 4*kg+r
    f16x4 A00, A01, A10, A11;                   // [j-half][k-half]
#pragma unroll
    for (int r = 0; r < 4; ++r) {
        A00[r] = (_Float16)Wh[(4 * kg + r)      * HID + bq];        // j 0-15,  i 0-15
        A01[r] = (_Float16)Wh[(16 + 4 * kg + r) * HID + bq];        // j 0-15,  i 16-31
        A10[r] = (_Float16)Wh[(4 * kg + r)      * HID + 16 + bq];   // j 16-31, i 0-15
        A11[r] = (_Float16)Wh[(16 + 4 * kg + r) * HID + 16 + bq];   // j 16-31, i 16-31
    }

    const int*   xb = x + (bt + bq) * TLEN;     // lanes 16+ dup lanes 0-15
    const float* Pg = P + 4 * kg;               // lane's j-quad base in a P row

    // token quads
    int4 tq_cur = *(const int4*)(xb);           // steps 0..3
    int4 tq_nxt = *(const int4*)(xb + 4);       // steps 4..7

    // P for quad 0 (prologue latency accepted once)
    f32x4 pc0a = *(const f32x4*)(Pg + tq_cur.x * HID);
    f32x4 pc0b = *(const f32x4*)(Pg + tq_cur.x * HID + 16);
    f32x4 pc1a = *(const f32x4*)(Pg + tq_cur.y * HID);
    f32x4 pc1b = *(const f32x4*)(Pg + tq_cur.y * HID + 16);
    f32x4 pc2a = *(const f32x4*)(Pg + tq_cur.z * HID);
    f32x4 pc2b = *(const f32x4*)(Pg + tq_cur.z * HID + 16);
    f32x4 pc3a = *(const f32x4*)(Pg + tq_cur.w * HID);
    f32x4 pc3b = *(const f32x4*)(Pg + tq_cur.w * HID + 16);

    f16x4 B0 = {};                              // h^T, i 0-15  (starts at 0)
    f16x4 B1 = {};                              // h^T, i 16-31
    const f32x4 ZV = {0.0f, 0.0f, 0.0f, 0.0f};

    const float TWO_LOG2E = 2.8853900817779268f;   // 2*log2(e)

#define TANH(Z) ({ float _e2 = __builtin_amdgcn_exp2f((Z) * TWO_LOG2E);       \
                   fmaf(-2.0f, __builtin_amdgcn_rcpf(_e2 + 1.0f), 1.0f); })

#define STEP(PA, PB)                                                          \
    {                                                                         \
        f32x4 z0a = __builtin_amdgcn_mfma_f32_16x16x16f16(A00, B0, (PA), 0, 0, 0); \
        f32x4 z0b = __builtin_amdgcn_mfma_f32_16x16x16f16(A01, B1, ZV,   0, 0, 0); \
        f32x4 z1a = __builtin_amdgcn_mfma_f32_16x16x16f16(A10, B0, (PB), 0, 0, 0); \
        f32x4 z1b = __builtin_amdgcn_mfma_f32_16x16x16f16(A11, B1, ZV,   0, 0, 0); \
        f32x4 z0 = z0a + z0b;                                                 \
        f32x4 z1 = z1a + z1b;                                                 \
        float t00 = TANH(z0[0]), t01 = TANH(z0[1]);                           \
        float t02 = TANH(z0[2]), t03 = TANH(z0[3]);                           \
        float t10 = TANH(z1[0]), t11 = TANH(z1[1]);                           \
        float t12 = TANH(z1[2]), t13 = TANH(z1[3]);                           \
        f16x2 q0 = __builtin_bit_cast(f16x2, __builtin_amdgcn_cvt_pkrtz(t00, t01)); \
        f16x2 q1 = __builtin_bit_cast(f16x2, __builtin_amdgcn_cvt_pkrtz(t02, t03)); \
        f16x2 q2 = __builtin_bit_cast(f16x2, __builtin_amdgcn_cvt_pkrtz(t10, t11)); \
        f16x2 q3 = __builtin_bit_cast(f16x2, __builtin_amdgcn_cvt_pkrtz(t12, t13)); \
        B0 = __builtin_shufflevector(q0, q1, 0, 1, 2, 3);                     \
        B1 = __builtin_shufflevector(q2, q3, 0, 1, 2, 3);                     \
    }

    const int NQ = TLEN / 4;                    // 128 quads, exact

    for (int k = 0; k < NQ; ++k) {
        // prefetch P for quad k+1 (tokens already resident in tq_nxt)
        f32x4 pn0a = *(const f32x4*)(Pg + tq_nxt.x * HID);
        f32x4 pn0b = *(const f32x4*)(Pg + tq_nxt.x * HID + 16);
        f32x4 pn1a = *(const f32x4*)(Pg + tq_nxt.y * HID);
        f32x4 pn1b = *(const f32x4*)(Pg + tq_nxt.y * HID + 16);
        f32x4 pn2a = *(const f32x4*)(Pg + tq_nxt.z * HID);
        f32x4 pn2b = *(const f32x4*)(Pg + tq_nxt.z * HID + 16);
        f32x4 pn3a = *(const f32x4*)(Pg + tq_nxt.w * HID);
        f32x4 pn3b = *(const f32x4*)(Pg + tq_nxt.w * HID + 16);
        // prefetch token quad k+2 (clamped; tail values unused)
        int  q2i = (k + 2 < NQ) ? (k + 2) : (NQ - 1);
        int4 tq2 = *(const int4*)(xb + 4 * q2i);

        STEP(pc0a, pc0b)
        STEP(pc1a, pc1b)
        STEP(pc2a, pc2b)
        STEP(pc3a, pc3b)

        pc0a = pn0a; pc0b = pn0b; pc1a = pn1a; pc1b = pn1b;
        pc2a = pn2a; pc2b = pn2b; pc3a = pn3a; pc3b = pn3b;
        tq_nxt = tq2;
    }
#undef STEP
#undef TANH

    // h^T[j][b]: B0 -> j = 4*kg+r, B1 -> j = 16+4*kg+r, b = bt + (l&15)
    // out[b] = sigmoid(sum_j h[b][j] * Wd[j] + bd)
    float s = 0.0f;
#pragma unroll
    for (int r = 0; r < 4; ++r) {
        s = fmaf((float)B0[r], Wd[4 * kg + r],      s);
        s = fmaf((float)B1[r], Wd[16 + 4 * kg + r], s);
    }
    s += __shfl_xor(s, 16, 64);                 // reduce over the 4 kg-groups
    s += __shfl_xor(s, 32, 64);
    if (l < 16) {
        float logit = s + bd[0];
        out[bt + l] = 1.0f / (1.0f + __expf(-logit));
    }
}

// ---------------------------------------------------------------------------
extern "C" void kernel_launch(void* const* d_in, const int* in_sizes, int n_in,
                              void* d_out, int out_size, void* d_ws, size_t ws_size,
                              hipStream_t stream)
{
    const int*   x   = (const int*)  d_in[0];
    const float* emb = (const float*)d_in[1];
    const float* Wx  = (const float*)d_in[2];
    const float* Wh  = (const float*)d_in[3];
    const float* bia = (const float*)d_in[4];
    const float* Wd  = (const float*)d_in[5];
    const float* bd  = (const float*)d_in[6];
    float* out = (float*)d_out;

    float* P = (float*)d_ws;                    // VOCAB*HID*4 = 1.28 MB

    rnn_proj<<<(VOCAB * HID + 255) / 256, 256, 0, stream>>>(emb, Wx, bia, P);
    rnn_scan<<<BATCH / 16, 64, 0, stream>>>(x, P, Wh, Wd, bd, out);
}

// Round 16
// 84.618 us; speedup vs baseline: 1.4374x; 1.4374x over previous
//
#include <hip/hip_runtime.h>

#define VOCAB 10000
#define EMB   16
#define HID   32
#define BATCH 4096
#define TLEN  512

typedef _Float16 f16x2 __attribute__((ext_vector_type(2)));
typedef _Float16 f16x8 __attribute__((ext_vector_type(8)));

#define TWO_LOG2E 2.8853900817779268f   /* 2*log2(e) */

// ---------------------------------------------------------------------------
// Kernel 1: P'[v][j] = (b[j] + sum_e emb[v][e]*Wx[e][j]) * 2log2e
// The 2log2e fold lets the scan feed exp2 directly (tanh via e^{2z}).
// ---------------------------------------------------------------------------
__global__ __launch_bounds__(256) void rnn_proj(
    const float* __restrict__ emb, const float* __restrict__ Wx,
    const float* __restrict__ bias, float* __restrict__ P)
{
    int tid = blockIdx.x * 256 + threadIdx.x;
    if (tid >= VOCAB * HID) return;
    int v = tid >> 5;
    int j = tid & 31;
    float acc = bias[j];
    const float* ev = emb + v * EMB;
#pragma unroll
    for (int e = 0; e < EMB; ++e) {
        acc = fmaf(ev[e], Wx[e * HID + j], acc);
    }
    P[tid] = acc * TWO_LOG2E;
}

// ---------------------------------------------------------------------------
// Kernel 2: fp16/fdot2 scan (r11 structure, issue-shaved).
// Wave = 2 batches x 32 j-lanes, full 32-MAC dot per lane (16 v_dot2_f32_f16,
// f32 accumulate), no shuffles, no barriers (wave-private LDS rows).
// Issue shaves vs r11:
//   - 2log2e folded into P (proj) and Wh (register init): z' = a0+a1 feeds
//     exp2 directly, no per-step multiply. |w*2.885| < 2.1 -> f16-safe.
//   - 2 accumulators + 1 add (was 4 accs + 3 adds); depth-8 dot chain is
//     hidden by the co-resident wave.
// Keeps: f16 h row (64 B, 4 ds_read_b128), quad unroll, int4 token loads,
// P prefetched one quad ahead, asm-pinned weights, waves_per_eu(2,2).
// ---------------------------------------------------------------------------
__global__ __launch_bounds__(256)
__attribute__((amdgpu_waves_per_eu(2, 2)))
void rnn_scan(
    const int*   __restrict__ x,   const float* __restrict__ P,
    const float* __restrict__ Wh,  const float* __restrict__ Wd,
    const float* __restrict__ bd,  float* __restrict__ out)
{
    __shared__ _Float16 h_lds[8][HID];          // 8 rows x 64 B

    const int lane = threadIdx.x & 63;
    const int wave = threadIdx.x >> 6;
    const int half = lane >> 5;
    const int j    = lane & 31;
    const int hb   = wave * 2 + half;           // wave-private row
    const int b    = blockIdx.x * 8 + hb;

    // Wh column j, pre-scaled by 2log2e, as fp16 pairs
    f16x2 wh2[16];
#pragma unroll
    for (int m = 0; m < 16; ++m) {
        wh2[m] = (f16x2){ (_Float16)(Wh[(2 * m + 0) * HID + j] * TWO_LOG2E),
                          (_Float16)(Wh[(2 * m + 1) * HID + j] * TWO_LOG2E) };
    }
#pragma unroll
    for (int m = 0; m < 16; ++m) asm("" : "+v"(wh2[m]));  // remat-proof

    h_lds[hb][j] = (_Float16)0.0f;              // h0 = 0 (wave-private)

    const int* xb = x + b * TLEN;

    // pipeline prologue: tokens for quads 0/1, P' for quad 0
    int4 tq_cur = *(const int4*)(xb);
    int4 tq_nxt = *(const int4*)(xb + 4);
    float pc0 = P[tq_cur.x * HID + j];
    float pc1 = P[tq_cur.y * HID + j];
    float pc2 = P[tq_cur.z * HID + j];
    float pc3 = P[tq_cur.w * HID + j];

    float hj = 0.0f;
    const f16x8* hrow = (const f16x8*)(&h_lds[hb][0]);

#define PAIR(U, A, B) __builtin_shufflevector((U), (U), (A), (B))
#define STEP(PV)                                                              \
    {                                                                         \
        f16x8 u0 = hrow[0], u1 = hrow[1], u2 = hrow[2], u3 = hrow[3];         \
        float a0 = (PV), a1 = 0.f;                                            \
        a0 = __builtin_amdgcn_fdot2(PAIR(u0,0,1), wh2[0],  a0, false);        \
        a1 = __builtin_amdgcn_fdot2(PAIR(u0,2,3), wh2[1],  a1, false);        \
        a0 = __builtin_amdgcn_fdot2(PAIR(u0,4,5), wh2[2],  a0, false);        \
        a1 = __builtin_amdgcn_fdot2(PAIR(u0,6,7), wh2[3],  a1, false);        \
        a0 = __builtin_amdgcn_fdot2(PAIR(u1,0,1), wh2[4],  a0, false);        \
        a1 = __builtin_amdgcn_fdot2(PAIR(u1,2,3), wh2[5],  a1, false);        \
        a0 = __builtin_amdgcn_fdot2(PAIR(u1,4,5), wh2[6],  a0, false);        \
        a1 = __builtin_amdgcn_fdot2(PAIR(u1,6,7), wh2[7],  a1, false);        \
        a0 = __builtin_amdgcn_fdot2(PAIR(u2,0,1), wh2[8],  a0, false);        \
        a1 = __builtin_amdgcn_fdot2(PAIR(u2,2,3), wh2[9],  a1, false);        \
        a0 = __builtin_amdgcn_fdot2(PAIR(u2,4,5), wh2[10], a0, false);        \
        a1 = __builtin_amdgcn_fdot2(PAIR(u2,6,7), wh2[11], a1, false);        \
        a0 = __builtin_amdgcn_fdot2(PAIR(u3,0,1), wh2[12], a0, false);        \
        a1 = __builtin_amdgcn_fdot2(PAIR(u3,2,3), wh2[13], a1, false);        \
        a0 = __builtin_amdgcn_fdot2(PAIR(u3,4,5), wh2[14], a0, false);        \
        a1 = __builtin_amdgcn_fdot2(PAIR(u3,6,7), wh2[15], a1, false);        \
        float z  = a0 + a1;                     /* already x 2log2e */        \
        float e2 = __builtin_amdgcn_exp2f(z);   /* = e^{2z_true} */           \
        float r  = __builtin_amdgcn_rcpf(e2 + 1.0f);                          \
        hj = fmaf(-2.0f, r, 1.0f);                                            \
        h_lds[hb][j] = (_Float16)hj;                                          \
    }

    const int NQ = TLEN / 4;                    // 128 quads, exact

    for (int k = 0; k < NQ; ++k) {
        // prefetch P' for quad k+1 (tokens already resident in tq_nxt)
        float pn0 = P[tq_nxt.x * HID + j];
        float pn1 = P[tq_nxt.y * HID + j];
        float pn2 = P[tq_nxt.z * HID + j];
        float pn3 = P[tq_nxt.w * HID + j];
        // prefetch token quad k+2 (clamped; tail values unused)
        int  q2i = (k + 2 < NQ) ? (k + 2) : (NQ - 1);
        int4 tq2 = *(const int4*)(xb + 4 * q2i);

        STEP(pc0)
        STEP(pc1)
        STEP(pc2)
        STEP(pc3)

        pc0 = pn0; pc1 = pn1; pc2 = pn2; pc3 = pn3;
        tq_nxt = tq2;
    }
#undef STEP
#undef PAIR

    // out[b] = sigmoid(sum_j h_j * Wd[j] + bd)
    float s = hj * Wd[j];
#pragma unroll
    for (int off = 16; off > 0; off >>= 1)
        s += __shfl_xor(s, off, 32);            // reduce within 32-lane half
    if (j == 0) {
        float logit = s + bd[0];
        out[b] = 1.0f / (1.0f + __expf(-logit)); // fp32 output
    }
}

// ---------------------------------------------------------------------------
extern "C" void kernel_launch(void* const* d_in, const int* in_sizes, int n_in,
                              void* d_out, int out_size, void* d_ws, size_t ws_size,
                              hipStream_t stream)
{
    const int*   x   = (const int*)  d_in[0];
    const float* emb = (const float*)d_in[1];
    const float* Wx  = (const float*)d_in[2];
    const float* Wh  = (const float*)d_in[3];
    const float* bia = (const float*)d_in[4];
    const float* Wd  = (const float*)d_in[5];
    const float* bd  = (const float*)d_in[6];
    float* out = (float*)d_out;

    float* P = (float*)d_ws;                    // VOCAB*HID*4 = 1.28 MB (pre-scaled)

    rnn_proj<<<(VOCAB * HID + 255) / 256, 256, 0, stream>>>(emb, Wx, bia, P);
    rnn_scan<<<BATCH / 8, 256, 0, stream>>>(x, P, Wh, Wd, bd, out);
}